// Round 2
// baseline (373.775 us; speedup 1.0000x reference)
//
#include <hip/hip_runtime.h>

// Adaptive wavelet transform (db4, zero-pad, 5-level cascade, per-feature level select)
// B=32, S=4096, F=64. Layout (b, s, f), f contiguous -> one wave == one (b,n), lanes over f.
//
// Reference does: pad to 2*ceil((T+7)/2) (left 3 / right 3 for even T), VALID conv
// kernel 8 stride 2 -> output length T/2 exactly (T even at every level).
// Cascade lengths: 2048, 1024, 512, 256, 128. lo[n] = sum_i h[i]*x[2n+i-3].
//
// Output concat (floats): approx[BSF] | details[5*BSF] | high_freq[BSF] | low_freq[BSF]
// Intermediate lowpass buffers (lo1..lo4 = 7,864,320 floats) are staged inside the
// high_freq output region (8,388,608 floats), which is only written by the final kernel.

#define NB 32
#define NS 4096
#define NF 64
#define BSF (NB * NS * NF)

// H0/H1 = time-reversed db4 dec_lo / dec_hi (cross-correlation form)
__constant__ float c_h0[8] = {
     0.23037781330885523f,  0.7148465705525415f,   0.6308807679295904f,
    -0.02798376941698385f, -0.18703481171888114f,  0.030841381835986965f,
     0.032883011666982945f, -0.010597401784997278f};
__constant__ float c_h1[8] = {
    -0.010597401784997278f, -0.032883011666982945f, 0.030841381835986965f,
     0.18703481171888114f,  -0.02798376941698385f,  -0.6308807679295904f,
     0.7148465705525415f,   -0.23037781330885523f};

// lowpass length after lv levels
__constant__ int c_len[6] = {NS, 2048, 1024, 512, 256, 128};

__device__ __forceinline__ int get_level(const float* __restrict__ scores, int f) {
    // levels = clip(2 + round_half_even(score * 3), 2, 5)
    int lv = 2 + (int)rintf(scores[f] * 3.0f);
    return min(5, max(2, lv));
}

// One analysis level: reads `in` (Tin rows), writes lo (len_out rows, dense layout)
// and the full S-range of details[j-1] (masked by level, tail zeros).
// If levels[f] == j, also writes approx/low_freq heads (tails zeroed in finalize).
__global__ __launch_bounds__(256) void wavelet_level(
    const float* __restrict__ in, int Tin,
    float* __restrict__ lo_out, int len_out,
    float* __restrict__ det_j,
    float* __restrict__ approx, float* __restrict__ lowf,
    const float* __restrict__ scores, int j)
{
    int t = blockIdx.x * 256 + threadIdx.x;       // grid exactly covers BSF
    int f = t & (NF - 1);
    int rest = t >> 6;                            // b*NS + n
    int n = rest & (NS - 1);
    int b = rest >> 12;
    int lv = get_level(scores, f);

    if (n < len_out) {
        float lo = 0.f, hi = 0.f;
        int base = 2 * n - 3;                     // left pad = 3 at every level
#pragma unroll
        for (int i = 0; i < 8; ++i) {
            int m = base + i;
            if (m >= 0 && m < Tin) {              // wave-uniform (same n across wave)
                float v = in[(b * Tin + m) * NF + f];
                lo = fmaf(c_h0[i], v, lo);
                hi = fmaf(c_h1[i], v, hi);
            }
        }
        det_j[t] = (lv >= j) ? hi : 0.f;          // detail at level j kept iff j <= lv
        if (lo_out) lo_out[(b * len_out + n) * NF + f] = lo;
        if (lv == j) { approx[t] = lo; lowf[t] = lo; }
    } else {
        det_j[t] = 0.f;                           // detail tail zeros
    }
}

// Finalize: approx/low_freq tail zeros (s >= len[levels[f]]) and
// high_freq = sum of (already masked) details.
__global__ __launch_bounds__(256) void wavelet_final(
    float* __restrict__ out, const float* __restrict__ scores)
{
    int t = blockIdx.x * 256 + threadIdx.x;
    int f = t & (NF - 1);
    int rest = t >> 6;
    int n = rest & (NS - 1);
    int lv = get_level(scores, f);

    float* approx = out;
    const float* det = out + (size_t)BSF;
    float* hf = out + (size_t)6 * BSF;
    float* lf = out + (size_t)7 * BSF;

    if (n >= c_len[lv]) { approx[t] = 0.f; lf[t] = 0.f; }

    float acc = 0.f;
    if (n < 2048) {
        acc = det[t];                                  // level 1, always kept
        if (n < 1024) acc += det[(size_t)1 * BSF + t]; // level 2, always kept (lv >= 2)
        if (n < 512)  acc += det[(size_t)2 * BSF + t]; // stored pre-masked
        if (n < 256)  acc += det[(size_t)3 * BSF + t];
        if (n < 128)  acc += det[(size_t)4 * BSF + t];
    }
    hf[t] = acc;
}

extern "C" void kernel_launch(void* const* d_in, const int* in_sizes, int n_in,
                              void* d_out, int out_size, void* d_ws, size_t ws_size,
                              hipStream_t stream)
{
    const float* x      = (const float*)d_in[0];
    const float* scores = (const float*)d_in[1];
    float* out = (float*)d_out;

    float* approx = out;
    float* det    = out + (size_t)BSF;
    float* hf     = out + (size_t)6 * BSF;   // used as lo-scratch until finalize
    float* lf     = out + (size_t)7 * BSF;

    float* lo1 = hf;
    float* lo2 = lo1 + (size_t)NB * 2048 * NF;
    float* lo3 = lo2 + (size_t)NB * 1024 * NF;
    float* lo4 = lo3 + (size_t)NB * 512 * NF;
    // lo1..lo4 total 7,864,320 floats < BSF (8,388,608) -> fits in hf region.

    dim3 grid(BSF / 256), block(256);
    wavelet_level<<<grid, block, 0, stream>>>(x,   NS,   lo1,     2048, det + (size_t)0 * BSF, approx, lf, scores, 1);
    wavelet_level<<<grid, block, 0, stream>>>(lo1, 2048, lo2,     1024, det + (size_t)1 * BSF, approx, lf, scores, 2);
    wavelet_level<<<grid, block, 0, stream>>>(lo2, 1024, lo3,      512, det + (size_t)2 * BSF, approx, lf, scores, 3);
    wavelet_level<<<grid, block, 0, stream>>>(lo3, 512,  lo4,      256, det + (size_t)3 * BSF, approx, lf, scores, 4);
    wavelet_level<<<grid, block, 0, stream>>>(lo4, 256,  nullptr,  128, det + (size_t)4 * BSF, approx, lf, scores, 5);
    wavelet_final<<<grid, block, 0, stream>>>(out, scores);
}

// Round 3
// 314.485 us; speedup vs baseline: 1.1885x; 1.1885x over previous
//
#include <hip/hip_runtime.h>

// Adaptive db4 wavelet transform, 5-level cascade, per-feature level select.
// B=32, S=4096, F=64, layout (b,s,f) f-contiguous. All kernels vectorized
// float4 across f (16 B/lane). Cascade lengths 2048/1024/512/256/128,
// lo[n] = sum_i h[i] * x[2n+i-3] (zero outside [0,Tin)).
//
// Output concat: approx[BSF] | det1..det5[5*BSF] | high_freq[BSF] | low_freq[BSF]
// lo1..lo4 staged in d_ws (30 MiB). Final kernel fuses: level-5 conv, det5 store,
// high_freq = sum of masked details (det5 from registers), approx/low_freq
// written once full-width (gather lo_{lv[f]} per component).

#define NB 32
#define NS 4096
#define NF 64
#define BSF (NB * NS * NF)
#define NT4 (BSF / 4)

__constant__ float c_h0[8] = {
     0.23037781330885523f,  0.7148465705525415f,   0.6308807679295904f,
    -0.02798376941698385f, -0.18703481171888114f,  0.030841381835986965f,
     0.032883011666982945f, -0.010597401784997278f};
__constant__ float c_h1[8] = {
    -0.010597401784997278f, -0.032883011666982945f, 0.030841381835986965f,
     0.18703481171888114f,  -0.02798376941698385f,  -0.6308807679295904f,
     0.7148465705525415f,   -0.23037781330885523f};

__device__ __forceinline__ int get_level(const float* __restrict__ scores, int f) {
    int lv = 2 + (int)rintf(scores[f] * 3.0f);   // round-half-even, matches jnp
    return min(5, max(2, lv));
}

// One analysis level (J = 1..4). Reads `in` (TIN rows), writes lo (LEN rows)
// and the full S-range of det_J (masked for J>=3, tail zeros).
template <int J, int TIN, int LEN>
__global__ __launch_bounds__(256) void wl_level(
    const float4* __restrict__ in, float4* __restrict__ lo_out,
    float4* __restrict__ det, const float* __restrict__ scores)
{
    int t = blockIdx.x * 256 + threadIdx.x;   // grid covers NT4 exactly
    int f4 = t & 15;
    int rest = t >> 4;
    int n = rest & (NS - 1);
    int b = rest >> 12;

    float4 dv = {0.f, 0.f, 0.f, 0.f};
    if (n < LEN) {
        float4 lo = {0.f, 0.f, 0.f, 0.f}, hi = {0.f, 0.f, 0.f, 0.f};
        int base = 2 * n - 3;
#pragma unroll
        for (int i = 0; i < 8; ++i) {
            int m = base + i;
            if ((unsigned)m < (unsigned)TIN) {      // wave-uniform
                float4 v = in[(b * TIN + m) * (NF / 4) + f4];
                lo.x = fmaf(c_h0[i], v.x, lo.x);  hi.x = fmaf(c_h1[i], v.x, hi.x);
                lo.y = fmaf(c_h0[i], v.y, lo.y);  hi.y = fmaf(c_h1[i], v.y, hi.y);
                lo.z = fmaf(c_h0[i], v.z, lo.z);  hi.z = fmaf(c_h1[i], v.z, hi.z);
                lo.w = fmaf(c_h0[i], v.w, lo.w);  hi.w = fmaf(c_h1[i], v.w, hi.w);
            }
        }
        if (J >= 3) {                                // det_J kept iff lv[f] >= J
            int f0 = f4 * 4;
            if (get_level(scores, f0 + 0) < J) hi.x = 0.f;
            if (get_level(scores, f0 + 1) < J) hi.y = 0.f;
            if (get_level(scores, f0 + 2) < J) hi.z = 0.f;
            if (get_level(scores, f0 + 3) < J) hi.w = 0.f;
        }
        dv = hi;
        lo_out[(b * LEN + n) * (NF / 4) + f4] = lo;
    }
    det[t] = dv;
}

// Fused level-5 + finalize: det5, high_freq (det5 from registers),
// approx/low_freq written once full-width via per-component lo gather.
__global__ __launch_bounds__(256) void wl_final(
    const float* __restrict__ lo2s, const float* __restrict__ lo3s,
    const float* __restrict__ lo4s,
    const float4* __restrict__ det1, const float4* __restrict__ det2,
    const float4* __restrict__ det3, const float4* __restrict__ det4,
    float4* __restrict__ det5, float4* __restrict__ approx,
    float4* __restrict__ hf, float4* __restrict__ lf,
    const float* __restrict__ scores)
{
    int t = blockIdx.x * 256 + threadIdx.x;
    int f4 = t & 15;
    int rest = t >> 4;
    int n = rest & (NS - 1);
    int b = rest >> 12;
    int f0 = f4 * 4;

    int lv[4];
#pragma unroll
    for (int c = 0; c < 4; ++c) lv[c] = get_level(scores, f0 + c);

    const float4* lo4v = (const float4*)lo4s;
    float4 d5 = {0.f, 0.f, 0.f, 0.f};
    float4 lo5 = {0.f, 0.f, 0.f, 0.f};
    if (n < 128) {
        float4 hi = {0.f, 0.f, 0.f, 0.f};
        int base = 2 * n - 3;
#pragma unroll
        for (int i = 0; i < 8; ++i) {
            int m = base + i;
            if ((unsigned)m < 256u) {
                float4 v = lo4v[(b * 256 + m) * (NF / 4) + f4];
                lo5.x = fmaf(c_h0[i], v.x, lo5.x);  hi.x = fmaf(c_h1[i], v.x, hi.x);
                lo5.y = fmaf(c_h0[i], v.y, lo5.y);  hi.y = fmaf(c_h1[i], v.y, hi.y);
                lo5.z = fmaf(c_h0[i], v.z, lo5.z);  hi.z = fmaf(c_h1[i], v.z, hi.z);
                lo5.w = fmaf(c_h0[i], v.w, lo5.w);  hi.w = fmaf(c_h1[i], v.w, hi.w);
            }
        }
        d5.x = (lv[0] >= 5) ? hi.x : 0.f;
        d5.y = (lv[1] >= 5) ? hi.y : 0.f;
        d5.z = (lv[2] >= 5) ? hi.z : 0.f;
        d5.w = (lv[3] >= 5) ? hi.w : 0.f;
    }
    det5[t] = d5;

    // high_freq = sum of masked details (det1/det2 always kept since lv >= 2;
    // det3/det4 stored pre-masked; det5 masked in registers above).
    float4 acc = d5;                               // zero for n >= 128
    if (n < 2048) {
        float4 v1 = det1[t];
        acc.x += v1.x; acc.y += v1.y; acc.z += v1.z; acc.w += v1.w;
        if (n < 1024) { float4 v = det2[t]; acc.x += v.x; acc.y += v.y; acc.z += v.z; acc.w += v.w; }
        if (n < 512)  { float4 v = det3[t]; acc.x += v.x; acc.y += v.y; acc.z += v.z; acc.w += v.w; }
        if (n < 256)  { float4 v = det4[t]; acc.x += v.x; acc.y += v.y; acc.z += v.z; acc.w += v.w; }
    }
    hf[t] = acc;

    // approx / low_freq: component c = lowpass after lv[c] levels, zero tail.
    const float* lo5s = (const float*)&lo5;
    float a[4];
#pragma unroll
    for (int c = 0; c < 4; ++c) {
        int L = lv[c];
        int len = 2048 >> (L - 1);                 // 1024/512/256/128 for L=2..5
        float v = 0.f;
        if (n < len) {
            if (L == 5)      v = lo5s[c];          // this thread's own lo5
            else if (L == 4) v = lo4s[(b * 256 + n) * NF + f0 + c];
            else if (L == 3) v = lo3s[(b * 512 + n) * NF + f0 + c];
            else             v = lo2s[(b * 1024 + n) * NF + f0 + c];
        }
        a[c] = v;
    }
    float4 av = {a[0], a[1], a[2], a[3]};
    approx[t] = av;
    lf[t] = av;
}

extern "C" void kernel_launch(void* const* d_in, const int* in_sizes, int n_in,
                              void* d_out, int out_size, void* d_ws, size_t ws_size,
                              hipStream_t stream)
{
    const float* x      = (const float*)d_in[0];
    const float* scores = (const float*)d_in[1];
    float* out = (float*)d_out;
    float* ws  = (float*)d_ws;

    // lo scratch in workspace: 2048+1024+512+256 rows of 32*64 floats = 30 MiB
    float* lo1 = ws;
    float* lo2 = lo1 + (size_t)NB * 2048 * NF;
    float* lo3 = lo2 + (size_t)NB * 1024 * NF;
    float* lo4 = lo3 + (size_t)NB * 512 * NF;

    float4* det1 = (float4*)(out + (size_t)1 * BSF);
    float4* det2 = (float4*)(out + (size_t)2 * BSF);
    float4* det3 = (float4*)(out + (size_t)3 * BSF);
    float4* det4 = (float4*)(out + (size_t)4 * BSF);
    float4* det5 = (float4*)(out + (size_t)5 * BSF);
    float4* approx = (float4*)out;
    float4* hf   = (float4*)(out + (size_t)6 * BSF);
    float4* lf   = (float4*)(out + (size_t)7 * BSF);

    dim3 grid(NT4 / 256), block(256);
    wl_level<1, 4096, 2048><<<grid, block, 0, stream>>>((const float4*)x,   (float4*)lo1, det1, scores);
    wl_level<2, 2048, 1024><<<grid, block, 0, stream>>>((const float4*)lo1, (float4*)lo2, det2, scores);
    wl_level<3, 1024,  512><<<grid, block, 0, stream>>>((const float4*)lo2, (float4*)lo3, det3, scores);
    wl_level<4,  512,  256><<<grid, block, 0, stream>>>((const float4*)lo3, (float4*)lo4, det4, scores);
    wl_final<<<grid, block, 0, stream>>>(lo2, lo3, lo4, det1, det2, det3, det4,
                                         det5, approx, hf, lf, scores);
}